// Round 1
// 688.417 us; speedup vs baseline: 1.0212x; 1.0212x over previous
//
#include <hip/hip_runtime.h>
#include <math.h>

#define Bn  32
#define Cn  1536
#define Tn  2048
#define BNn 128
#define TSPLIT 4

typedef __attribute__((ext_vector_type(8))) short bf16x8;
typedef __attribute__((ext_vector_type(4))) float fx4;

// round-to-nearest-even fp32 -> bf16 (as ushort)
__device__ __forceinline__ unsigned int f2bf1(float f) {
    unsigned int u = __float_as_uint(f);
    return (u + 0x7fffu + ((u >> 16) & 1u)) >> 16;
}
__device__ __forceinline__ float fast_tanh(float v) {
    // 1 - 2/(e^{2v}+1); exact at +-inf saturation, ~1e-6 rel err
    return 1.f - 2.f / (__expf(2.f * v) + 1.f);
}

// ---------------------------------------------------------------------------
// Prep: convert W_tdnn (BN x C) and W_attn (C x BN) fp32 -> bf16.
// ---------------------------------------------------------------------------
__global__ void k_prep(const float* __restrict__ W1f, const float* __restrict__ Waf,
                       short* __restrict__ W1b, short* __restrict__ Wab) {
    int i = blockIdx.x * 256 + threadIdx.x;
    if (i < BNn * Cn) {
        W1b[i] = (short)f2bf1(W1f[i]);
        Wab[i] = (short)f2bf1(Waf[i]);
    }
}

// ---------------------------------------------------------------------------
// GEMM1: e[b][t][o] = tanh( sum_c x[b][c][t] * W[o][c] + bias[o] )   (e^T layout!)
// (unchanged from previous round)
// ---------------------------------------------------------------------------
__global__ __launch_bounds__(256, 2) void k_gemm1(
    const float* __restrict__ x, const short* __restrict__ W1,
    const float* __restrict__ bias, short* __restrict__ e)
{
    __shared__ short sA[128 * 64];  // [t][k] bf16, 16B blocks swizzled by ^(t&7)

    const int b    = blockIdx.y;
    const int t0   = blockIdx.x * 128;
    const int tid  = threadIdx.x;
    const int lane = tid & 63;
    const int wv   = tid >> 6;
    const int ln   = lane & 15;
    const int g    = lane >> 4;
    const int wt   = (wv & 1) * 64;
    const int wo   = (wv >> 1) * 64;

    const float* xb = x + (size_t)b * Cn * Tn + t0;

    const int t4 = (tid & 31) * 4;
    const int cq = (tid >> 5) * 4;

    fx4 acc[4][4];
    #pragma unroll
    for (int i = 0; i < 4; ++i)
        #pragma unroll
        for (int j = 0; j < 4; ++j) acc[i][j] = (fx4){0.f, 0.f, 0.f, 0.f};

    for (int k0 = 0; k0 < Cn; k0 += 64) {
        bf16x8 bfr[4][2];
        #pragma unroll
        for (int nn = 0; nn < 4; ++nn)
            #pragma unroll
            for (int kt = 0; kt < 2; ++kt)
                bfr[nn][kt] = *(const bf16x8*)(W1 + (size_t)(wo + nn * 16 + ln) * Cn
                                               + k0 + kt * 32 + g * 8);

        float4 xr[2][4];
        #pragma unroll
        for (int p = 0; p < 2; ++p) {
            const int c = cq + p * 32;
            #pragma unroll
            for (int j = 0; j < 4; ++j)
                xr[p][j] = *(const float4*)(xb + (size_t)(k0 + c + j) * Tn + t4);
        }
        __syncthreads();
        #pragma unroll
        for (int p = 0; p < 2; ++p) {
            const int c   = cq + p * 32;
            const int blk = c >> 3;
            const int sub = c & 7;
            #pragma unroll
            for (int i = 0; i < 4; ++i) {
                const int t = t4 + i;
                unsigned int lo = f2bf1(((const float*)&xr[p][0])[i]) |
                                  (f2bf1(((const float*)&xr[p][1])[i]) << 16);
                unsigned int hi = f2bf1(((const float*)&xr[p][2])[i]) |
                                  (f2bf1(((const float*)&xr[p][3])[i]) << 16);
                const int idx = t * 64 + ((blk ^ (t & 7)) << 3) + sub;
                *(uint2*)(sA + idx) = make_uint2(lo, hi);
            }
        }
        __syncthreads();

        #pragma unroll
        for (int kt = 0; kt < 2; ++kt) {
            bf16x8 af[4];
            #pragma unroll
            for (int mm = 0; mm < 4; ++mm) {
                const int t = wt + mm * 16 + ln;
                af[mm] = *(const bf16x8*)(sA + t * 64 + (((kt * 4 + g) ^ (t & 7)) << 3));
            }
            #pragma unroll
            for (int mm = 0; mm < 4; ++mm)
                #pragma unroll
                for (int nn = 0; nn < 4; ++nn)
                    acc[mm][nn] = __builtin_amdgcn_mfma_f32_16x16x32_bf16(
                        af[mm], bfr[nn][kt], acc[mm][nn], 0, 0, 0);
        }
    }

    float bs[4];
    #pragma unroll
    for (int nn = 0; nn < 4; ++nn) bs[nn] = bias[wo + nn * 16 + ln];

    short* eb = e + ((size_t)b * Tn + t0 + wt) * BNn + wo;
    #pragma unroll
    for (int mm = 0; mm < 4; ++mm)
        #pragma unroll
        for (int nn = 0; nn < 4; ++nn) {
            #pragma unroll
            for (int r = 0; r < 4; ++r) {
                const int t = mm * 16 + g * 4 + r;
                const float v = fast_tanh(acc[mm][nn][r] + bs[nn]);
                eb[(size_t)t * BNn + nn * 16 + ln] = (short)f2bf1(v);
            }
        }
}

// ---------------------------------------------------------------------------
// Stage one 64t x 128k e-chunk directly global->LDS (16B granules).
// Source address carries the XOR swizzle; LDS dest is linear in lane order
// (wave-uniform base + lane*16), as global_load_lds requires.
// ---------------------------------------------------------------------------
__device__ __forceinline__ void stage_e(short* sbuf, const short* ebase,
                                        int tid, int ts0) {
    #pragma unroll
    for (int j = 0; j < 8; ++j) {
        const int p   = j * 128 + tid;
        const int t   = p >> 4;
        const int blk = (p & 15) ^ (t & 15);
        __builtin_amdgcn_global_load_lds(
            (const __attribute__((address_space(1))) unsigned int*)
                (ebase + (size_t)(ts0 + t) * BNn + blk * 8),
            (__attribute__((address_space(3))) unsigned int*)(sbuf + p * 8),
            16, 0, 0);
    }
}

// ---------------------------------------------------------------------------
// Kernel 2: a = Wa_bf16 @ e^T (MFMA, K=128), mask, per-lane online softmax,
// weighted mean/std partials of fp32 x. Block = 128 thr (2 waves), c-tile 64.
// NEW: T split 4-ways across blockIdx.z (grid 3072 blocks), double-buffered
// direct-to-LDS e staging, single raw barrier per iteration. Writes online-
// softmax partials (m, S0, S1, S2) to workspace; k_merge folds the 4 splits.
// ---------------------------------------------------------------------------
__global__ __launch_bounds__(128, 3) void k_attn2(
    const float* __restrict__ x, const short* __restrict__ e,
    const short* __restrict__ Wab, const int* __restrict__ mask,
    float* __restrict__ part)
{
    __shared__ short sE[2][64 * 128];  // double-buffered [t][k] bf16, swizzled

    const int b    = blockIdx.y;
    const int c0   = blockIdx.x * 64;
    const int tbeg = blockIdx.z * (Tn / TSPLIT);
    const int tid  = threadIdx.x;
    const int lane = tid & 63;
    const int wv   = tid >> 6;
    const int ln   = lane & 15;
    const int g    = lane >> 4;
    const int cw   = c0 + wv * 32;

    const float* xb    = x + (size_t)b * Cn * Tn;
    const short* ebase = e + (size_t)b * Tn * BNn;
    const int*   mb    = mask + (size_t)b * Tn;

    // A frags (Wa rows, K=128) resident in registers for the whole kernel
    bf16x8 af[2][4];
    #pragma unroll
    for (int mt = 0; mt < 2; ++mt)
        #pragma unroll
        for (int kt = 0; kt < 4; ++kt)
            af[mt][kt] = *(const bf16x8*)(Wab + (size_t)(cw + mt * 16 + ln) * BNn
                                          + kt * 32 + g * 8);

    float mS[8], S0[8], S1[8], S2[8];
    #pragma unroll
    for (int s = 0; s < 8; ++s) { mS[s] = -1e30f; S0[s] = 0.f; S1[s] = 0.f; S2[s] = 0.f; }

    stage_e(sE[0], ebase, tid, tbeg);
    int cur = 0;

    for (int it = 0; it < (Tn / TSPLIT) / 64; ++it) {
        const int t0 = tbeg + it * 64;
        // buf[cur]'s stage (issued last iter) lands; prev frag reads complete
        asm volatile("s_waitcnt vmcnt(0)" ::: "memory");
        __builtin_amdgcn_s_barrier();
        if (it + 1 < (Tn / TSPLIT) / 64)
            stage_e(sE[cur ^ 1], ebase, tid, t0 + 64);   // hides under compute

        // prefetch x (this lane's 8 c-rows x 4 t's) and mask
        float xv[2][4][4];
        #pragma unroll
        for (int mt = 0; mt < 2; ++mt)
            #pragma unroll
            for (int r = 0; r < 4; ++r) {
                const float* xr = xb + (size_t)(cw + mt * 16 + g * 4 + r) * Tn + t0 + ln;
                #pragma unroll
                for (int nt = 0; nt < 4; ++nt) xv[mt][r][nt] = xr[nt * 16];
            }
        int mv4[4];
        #pragma unroll
        for (int nt = 0; nt < 4; ++nt) mv4[nt] = mb[t0 + nt * 16 + ln];

        fx4 acc[2][4];
        #pragma unroll
        for (int mt = 0; mt < 2; ++mt)
            #pragma unroll
            for (int nt = 0; nt < 4; ++nt) acc[mt][nt] = (fx4){0.f, 0.f, 0.f, 0.f};

        #pragma unroll
        for (int kt = 0; kt < 4; ++kt) {
            bf16x8 bfr[4];
            #pragma unroll
            for (int nt = 0; nt < 4; ++nt) {
                const int t = nt * 16 + ln;
                bfr[nt] = *(const bf16x8*)(sE[cur] + t * 128
                                           + (((kt * 4 + g) ^ (t & 15)) << 3));
            }
            #pragma unroll
            for (int mt = 0; mt < 2; ++mt)
                #pragma unroll
                for (int nt = 0; nt < 4; ++nt)
                    acc[mt][nt] = __builtin_amdgcn_mfma_f32_16x16x32_bf16(
                        af[mt][kt], bfr[nt], acc[mt][nt], 0, 0, 0);
        }

        // online softmax + stats update (per lane, no cross-lane in loop)
        #pragma unroll
        for (int mt = 0; mt < 2; ++mt)
            #pragma unroll
            for (int r = 0; r < 4; ++r) {
                const int s = mt * 4 + r;
                float a0 = mv4[0] ? -1e9f : acc[mt][0][r];
                float a1 = mv4[1] ? -1e9f : acc[mt][1][r];
                float a2 = mv4[2] ? -1e9f : acc[mt][2][r];
                float a3 = mv4[3] ? -1e9f : acc[mt][3][r];
                const float mc = fmaxf(fmaxf(a0, a1), fmaxf(a2, a3));
                const float mn = fmaxf(mS[s], mc);
                const float sc = __expf(mS[s] - mn);
                const float p0 = __expf(a0 - mn), p1 = __expf(a1 - mn);
                const float p2 = __expf(a2 - mn), p3 = __expf(a3 - mn);
                const float x0 = xv[mt][r][0], x1 = xv[mt][r][1];
                const float x2 = xv[mt][r][2], x3 = xv[mt][r][3];
                S0[s] = S0[s] * sc + (p0 + p1 + p2 + p3);
                S1[s] = S1[s] * sc + (p0 * x0 + p1 * x1 + p2 * x2 + p3 * x3);
                S2[s] = S2[s] * sc + (p0 * x0 * x0 + p1 * x1 * x1 + p2 * x2 * x2 + p3 * x3 * x3);
                mS[s] = mn;
            }
        cur ^= 1;
    }

    // merge the 16 t-partitions (lanes with same g), write split partial
    #pragma unroll
    for (int s = 0; s < 8; ++s) {
        float m = mS[s], s0 = S0[s], s1 = S1[s], s2 = S2[s];
        #pragma unroll
        for (int off = 1; off < 16; off <<= 1) {
            const float mo = __shfl_xor(m, off);
            const float q0 = __shfl_xor(s0, off);
            const float q1 = __shfl_xor(s1, off);
            const float q2 = __shfl_xor(s2, off);
            const float mn = fmaxf(m, mo);
            const float ea = __expf(m - mn), eb2 = __expf(mo - mn);
            s0 = s0 * ea + q0 * eb2;
            s1 = s1 * ea + q1 * eb2;
            s2 = s2 * ea + q2 * eb2;
            m = mn;
        }
        if (ln == 0) {
            const int c = cw + (s >> 2) * 16 + g * 4 + (s & 3);
            *(float4*)&part[(((size_t)b * TSPLIT + blockIdx.z) * Cn + c) * 4] =
                make_float4(m, s0, s1, s2);
        }
    }
}

// ---------------------------------------------------------------------------
// Merge the TSPLIT online-softmax partials per (b,c) -> mean/std output.
// ---------------------------------------------------------------------------
__global__ void k_merge(const float* __restrict__ part, float* __restrict__ out) {
    const int i = blockIdx.x * 256 + threadIdx.x;
    if (i >= Bn * Cn) return;
    const int b = i / Cn, c = i - b * Cn;
    float m = -1e30f, s0 = 0.f, s1 = 0.f, s2 = 0.f;
    #pragma unroll
    for (int sp = 0; sp < TSPLIT; ++sp) {
        const float4 v = *(const float4*)&part[(((size_t)b * TSPLIT + sp) * Cn + c) * 4];
        const float mn = fmaxf(m, v.x);
        const float ea = __expf(m - mn), eb = __expf(v.x - mn);
        s0 = s0 * ea + v.y * eb;
        s1 = s1 * ea + v.z * eb;
        s2 = s2 * ea + v.w * eb;
        m = mn;
    }
    const float mean = s1 / s0;
    const float var  = fmaxf(s2 / s0 - mean * mean, 1e-9f);
    out[(size_t)b * (2 * Cn) + c]      = mean;
    out[(size_t)b * (2 * Cn) + Cn + c] = sqrtf(var);
}

extern "C" void kernel_launch(void* const* d_in, const int* in_sizes, int n_in,
                              void* d_out, int out_size, void* d_ws, size_t ws_size,
                              hipStream_t stream) {
    const float* x      = (const float*)d_in[0];
    const int*   mask   = (const int*)d_in[1];
    const float* W_tdnn = (const float*)d_in[2];
    const float* b_tdnn = (const float*)d_in[3];
    const float* W_attn = (const float*)d_in[4];
    // d_in[5] = b_attn: constant over t per row -> cancels in softmax. Unused.
    float* out = (float*)d_out;

    short* e_bf = (short*)d_ws;                                        // B*T*BN bf16 = 16.78 MB
    short* W1b  = (short*)((char*)d_ws + (size_t)Bn * Tn * BNn * 2);   // BN*C bf16
    short* Wab  = W1b + (size_t)BNn * Cn;                              // C*BN bf16
    float* part = (float*)(Wab + (size_t)BNn * Cn);                    // B*TSPLIT*C*4 f32 = 3.15 MB

    k_prep<<<dim3((BNn * Cn + 255) / 256), 256, 0, stream>>>(W_tdnn, W_attn, W1b, Wab);
    k_gemm1<<<dim3(Tn / 128, Bn), 256, 0, stream>>>(x, W1b, b_tdnn, e_bf);
    k_attn2<<<dim3(Cn / 64, Bn, TSPLIT), 128, 0, stream>>>(x, e_bf, Wab, mask, part);
    k_merge<<<dim3((Bn * Cn + 255) / 256), 256, 0, stream>>>(part, out);
}

// Round 4
// 629.371 us; speedup vs baseline: 1.1170x; 1.0938x over previous
//
#include <hip/hip_runtime.h>
#include <math.h>

#define Bn  32
#define Cn  1536
#define Tn  2048
#define BNn 128
#define SHIFT 12.0f

typedef __attribute__((ext_vector_type(8))) short bf16x8;
typedef __attribute__((ext_vector_type(4))) float fx4;

// round-to-nearest-even fp32 -> bf16 (as ushort)
__device__ __forceinline__ unsigned int f2bf1(float f) {
    unsigned int u = __float_as_uint(f);
    return (u + 0x7fffu + ((u >> 16) & 1u)) >> 16;
}
__device__ __forceinline__ float fast_tanh(float v) {
    // 1 - 2/(e^{2v}+1); exact at +-inf saturation, ~1e-6 rel err
    return 1.f - 2.f / (__expf(2.f * v) + 1.f);
}

// ---------------------------------------------------------------------------
// Prep: convert W_tdnn (BN x C) and W_attn (C x BN) fp32 -> bf16.
// ---------------------------------------------------------------------------
__global__ void k_prep(const float* __restrict__ W1f, const float* __restrict__ Waf,
                       short* __restrict__ W1b, short* __restrict__ Wab) {
    int i = blockIdx.x * 256 + threadIdx.x;
    if (i < BNn * Cn) {
        W1b[i] = (short)f2bf1(W1f[i]);
        Wab[i] = (short)f2bf1(Waf[i]);
    }
}

// ---------------------------------------------------------------------------
// Fused kernel. Block = (b, 128-t tile), 256 threads (4 waves, 2x2).
//
// Phase 1: e[t][o] = tanh(W1 @ x + b) for the block's 128-t tile, all 128 o.
// Result goes to LDS sE[t][o] (bf16, 16B-block XOR swizzle by ^(t&15)).
//
// Phase 2: a[t][c] = e[t][:] . Wa[c][:] via MFMA with A = e-tile (LDS->reg
// once, reused for all 24 c-chunks), B = Wa rows direct from global (L2).
// D[m=t][n=c] => lane's 4 acc values are 4 CONSECUTIVE t for one c => x
// loads for stats are float4, mask int4 loaded once. Fixed-shift softmax
// (|a| <= ||Wa_c||*||e_t|| <= ~11.3 since |e|<1), partials are plain sums.
// ---------------------------------------------------------------------------
__global__ __launch_bounds__(256, 2) void k_fused(
    const float* __restrict__ x, const short* __restrict__ W1,
    const float* __restrict__ bias, const short* __restrict__ Wab,
    const int* __restrict__ mask, float* __restrict__ part)
{
    __shared__ short sA[128 * 64];   // phase-1 x^T staging, ^(t&7) swizzle
    __shared__ short sE[128 * 128];  // e-tile [t][o], ^(t&15) swizzle

    const int b    = blockIdx.y;
    const int t0g  = blockIdx.x * 128;
    const int tid  = threadIdx.x;
    const int lane = tid & 63;
    const int wv   = tid >> 6;
    const int ln   = lane & 15;
    const int g    = lane >> 4;
    const int wt   = (wv & 1) * 64;   // t-half (both phases)
    const int wo   = (wv >> 1) * 64;  // phase-1 o-half

    const float* xb = x + (size_t)b * Cn * Tn;
    const float* xt = xb + t0g;

    const int t4 = (tid & 31) * 4;
    const int cq = (tid >> 5) * 4;

    // ---------------- phase 1: e-tile via MFMA over K=C ----------------
    fx4 acc[4][4];
    #pragma unroll
    for (int i = 0; i < 4; ++i)
        #pragma unroll
        for (int j = 0; j < 4; ++j) acc[i][j] = (fx4){0.f, 0.f, 0.f, 0.f};

    for (int k0 = 0; k0 < Cn; k0 += 64) {
        bf16x8 bfr[4][2];
        #pragma unroll
        for (int nn = 0; nn < 4; ++nn)
            #pragma unroll
            for (int kt = 0; kt < 2; ++kt)
                bfr[nn][kt] = *(const bf16x8*)(W1 + (size_t)(wo + nn * 16 + ln) * Cn
                                               + k0 + kt * 32 + g * 8);

        float4 xr[2][4];
        #pragma unroll
        for (int p = 0; p < 2; ++p) {
            const int c = cq + p * 32;
            #pragma unroll
            for (int j = 0; j < 4; ++j)
                xr[p][j] = *(const float4*)(xt + (size_t)(k0 + c + j) * Tn + t4);
        }
        __syncthreads();
        #pragma unroll
        for (int p = 0; p < 2; ++p) {
            const int c   = cq + p * 32;
            const int blk = c >> 3;
            const int sub = c & 7;
            #pragma unroll
            for (int i = 0; i < 4; ++i) {
                const int t = t4 + i;
                unsigned int lo = f2bf1(((const float*)&xr[p][0])[i]) |
                                  (f2bf1(((const float*)&xr[p][1])[i]) << 16);
                unsigned int hi = f2bf1(((const float*)&xr[p][2])[i]) |
                                  (f2bf1(((const float*)&xr[p][3])[i]) << 16);
                const int idx = t * 64 + ((blk ^ (t & 7)) << 3) + sub;
                *(uint2*)(sA + idx) = make_uint2(lo, hi);
            }
        }
        __syncthreads();

        #pragma unroll
        for (int kt = 0; kt < 2; ++kt) {
            bf16x8 af[4];
            #pragma unroll
            for (int mm = 0; mm < 4; ++mm) {
                const int t = wt + mm * 16 + ln;
                af[mm] = *(const bf16x8*)(sA + t * 64 + (((kt * 4 + g) ^ (t & 7)) << 3));
            }
            #pragma unroll
            for (int mm = 0; mm < 4; ++mm)
                #pragma unroll
                for (int nn = 0; nn < 4; ++nn)
                    acc[mm][nn] = __builtin_amdgcn_mfma_f32_16x16x32_bf16(
                        af[mm], bfr[nn][kt], acc[mm][nn], 0, 0, 0);
        }
    }

    // epilogue: bias + tanh -> sE[t][o], 16B-block swizzle ^(t&15)
    float bs[4];
    #pragma unroll
    for (int nn = 0; nn < 4; ++nn) bs[nn] = bias[wo + nn * 16 + ln];

    #pragma unroll
    for (int mm = 0; mm < 4; ++mm)
        #pragma unroll
        for (int nn = 0; nn < 4; ++nn) {
            #pragma unroll
            for (int r = 0; r < 4; ++r) {
                const int t = wt + mm * 16 + g * 4 + r;
                const int o = wo + nn * 16 + ln;
                const float v = fast_tanh(acc[mm][nn][r] + bs[nn]);
                sE[t * 128 + (((o >> 3) ^ (t & 15)) << 3) + (o & 7)] = (short)f2bf1(v);
            }
        }
    __syncthreads();

    // ---------------- phase 2: scores + stats, barrier-free loop -------
    // A-frags: this wave's 64-t half of the e-tile, K=128, loaded once.
    bf16x8 af2[4][4];
    #pragma unroll
    for (int mt = 0; mt < 4; ++mt)
        #pragma unroll
        for (int kt = 0; kt < 4; ++kt) {
            const int t = wt + mt * 16 + ln;
            af2[mt][kt] = *(const bf16x8*)(sE + t * 128 + (((kt * 4 + g) ^ (t & 15)) << 3));
        }

    // masks for this lane's 16 t's (fixed across c-chunks)
    int4 mv[4];
    #pragma unroll
    for (int mt = 0; mt < 4; ++mt)
        mv[mt] = *(const int4*)(mask + (size_t)b * Tn + t0g + wt + mt * 16 + g * 4);

    const int wc    = (wv >> 1) * 32;            // c-half within 64-chunk
    const int chunk = blockIdx.x * 2 + (wv & 1); // 32 t-half chunks per (b)

    for (int c0 = 0; c0 < Cn; c0 += 64) {
        // B-frags: Wa rows (k=o contiguous), L2-resident
        bf16x8 bfr[2][4];
        #pragma unroll
        for (int nt = 0; nt < 2; ++nt)
            #pragma unroll
            for (int kt = 0; kt < 4; ++kt)
                bfr[nt][kt] = *(const bf16x8*)(Wab + (size_t)(c0 + wc + nt * 16 + ln) * BNn
                                               + kt * 32 + g * 8);

        // x for stats: lane's 4 consecutive t per (mt,nt) -> float4 (cache-hot)
        float4 xq[4][2];
        #pragma unroll
        for (int mt = 0; mt < 4; ++mt)
            #pragma unroll
            for (int nt = 0; nt < 2; ++nt)
                xq[mt][nt] = *(const float4*)(xb + (size_t)(c0 + wc + nt * 16 + ln) * Tn
                                              + t0g + wt + mt * 16 + g * 4);

        fx4 a2[4][2];
        #pragma unroll
        for (int mt = 0; mt < 4; ++mt)
            #pragma unroll
            for (int nt = 0; nt < 2; ++nt) a2[mt][nt] = (fx4){0.f, 0.f, 0.f, 0.f};

        #pragma unroll
        for (int kt = 0; kt < 4; ++kt)
            #pragma unroll
            for (int mt = 0; mt < 4; ++mt)
                #pragma unroll
                for (int nt = 0; nt < 2; ++nt)
                    a2[mt][nt] = __builtin_amdgcn_mfma_f32_16x16x32_bf16(
                        af2[mt][kt], bfr[nt][kt], a2[mt][nt], 0, 0, 0);

        // fixed-shift softmax partials over this wave's 64 t's
        #pragma unroll
        for (int nt = 0; nt < 2; ++nt) {
            float s0 = 0.f, s1 = 0.f, s2 = 0.f;
            #pragma unroll
            for (int mt = 0; mt < 4; ++mt) {
                #pragma unroll
                for (int r = 0; r < 4; ++r) {
                    const int msk = ((const int*)&mv[mt])[r];
                    const float p = msk ? 0.f : __expf(a2[mt][nt][r] - SHIFT);
                    const float xv = ((const float*)&xq[mt][nt])[r];
                    s0 += p;
                    s1 += p * xv;
                    s2 += p * xv * xv;
                }
            }
            // fold the 4 g-groups (t-partitions): plain sums, no rescale
            s0 += __shfl_xor(s0, 16); s1 += __shfl_xor(s1, 16); s2 += __shfl_xor(s2, 16);
            s0 += __shfl_xor(s0, 32); s1 += __shfl_xor(s1, 32); s2 += __shfl_xor(s2, 32);
            if (g == 0) {
                const int c = c0 + wc + nt * 16 + ln;
                *(float4*)&part[(((size_t)b * 32 + chunk) * Cn + c) * 4] =
                    make_float4(s0, s1, s2, 0.f);
            }
        }
    }
}

// ---------------------------------------------------------------------------
// Merge the 32 t-half-chunk partials per (b,c) -> mean/std output.
// ---------------------------------------------------------------------------
__global__ void k_merge(const float* __restrict__ part, float* __restrict__ out) {
    const int i = blockIdx.x * 256 + threadIdx.x;
    if (i >= Bn * Cn) return;
    const int b = i / Cn, c = i - b * Cn;
    float s0 = 0.f, s1 = 0.f, s2 = 0.f;
    #pragma unroll 8
    for (int sp = 0; sp < 32; ++sp) {
        const float4 v = *(const float4*)&part[(((size_t)b * 32 + sp) * Cn + c) * 4];
        s0 += v.x; s1 += v.y; s2 += v.z;
    }
    const float mean = s1 / s0;
    const float var  = fmaxf(s2 / s0 - mean * mean, 1e-9f);
    out[(size_t)b * (2 * Cn) + c]      = mean;
    out[(size_t)b * (2 * Cn) + Cn + c] = sqrtf(var);
}

extern "C" void kernel_launch(void* const* d_in, const int* in_sizes, int n_in,
                              void* d_out, int out_size, void* d_ws, size_t ws_size,
                              hipStream_t stream) {
    const float* x      = (const float*)d_in[0];
    const int*   mask   = (const int*)d_in[1];
    const float* W_tdnn = (const float*)d_in[2];
    const float* b_tdnn = (const float*)d_in[3];
    const float* W_attn = (const float*)d_in[4];
    // d_in[5] = b_attn: constant over t per row -> cancels in softmax. Unused.
    float* out = (float*)d_out;

    short* W1b  = (short*)d_ws;                     // BN*C bf16
    short* Wab  = W1b + (size_t)BNn * Cn;           // C*BN bf16
    float* part = (float*)(Wab + (size_t)BNn * Cn); // B*32*C*4 f32 = 25.2 MB

    k_prep<<<dim3((BNn * Cn + 255) / 256), 256, 0, stream>>>(W_tdnn, W_attn, W1b, Wab);
    k_fused<<<dim3(Tn / 128, Bn), 256, 0, stream>>>(x, W1b, b_tdnn, Wab, mask, part);
    k_merge<<<dim3((Bn * Cn + 255) / 256), 256, 0, stream>>>(part, out);
}